// Round 9
// baseline (645.907 us; speedup 1.0000x reference)
//
#include <hip/hip_runtime.h>
#include <hip/hip_fp16.h>

#define N_NODES 50000
#define N_EDGES 800000
#define D 64
#define NBUCK 196                 // ceil(N_NODES / 256)
#define BUCK_SHIFT 8
#define PA_CHUNK 2048
#define PA_BLOCKS ((N_EDGES + PA_CHUNK - 1) / PA_CHUNK)   // 391
#define PB_CAP 8192               // Poisson(4082) never reaches this; fallback kept anyway
#define PULL_BLOCKS 1024          // exactly 4 blocks/CU on 256 CUs -> co-resident

// ---- tiny init -------------------------------------------------------------
__global__ void zero_bhist(int* __restrict__ bhist) {
    int t = threadIdx.x;
    if (t < NBUCK) bhist[t] = 0;
}

// ---- coarse 196-bucket histogram of dst (LDS-privatized) -------------------
__global__ __launch_bounds__(256) void bucket_hist(const int* __restrict__ dst,
                                                   int* __restrict__ bhist) {
    __shared__ int h[NBUCK];
    for (int i = threadIdx.x; i < NBUCK; i += 256) h[i] = 0;
    __syncthreads();
    int stride = gridDim.x * 256;
    for (int e = blockIdx.x * 256 + threadIdx.x; e < N_EDGES; e += stride)
        atomicAdd(&h[dst[e] >> BUCK_SHIFT], 1);
    __syncthreads();
    for (int i = threadIdx.x; i < NBUCK; i += 256)
        if (h[i]) atomicAdd(&bhist[i], h[i]);
}

// ---- 1-block scan of 196 bucket counts -> bucketoff / bnext ---------------
__global__ __launch_bounds__(256) void bucket_scan(const int* __restrict__ bhist,
                                                   int* __restrict__ bucketoff,
                                                   int* __restrict__ bnext,
                                                   int* __restrict__ rowptr) {
    __shared__ int lds[256];
    int t = threadIdx.x;
    int v = (t < NBUCK) ? bhist[t] : 0;
    lds[t] = v;
    __syncthreads();
    for (int off = 1; off < 256; off <<= 1) {
        int u = (t >= off) ? lds[t - off] : 0;
        __syncthreads();
        lds[t] += u;
        __syncthreads();
    }
    if (t < NBUCK) { bucketoff[t] = lds[t] - v; bnext[t] = lds[t] - v; }
    if (t == 0)    { bucketoff[NBUCK] = N_EDGES; rowptr[N_NODES] = N_EDGES; }
}

// ---- pass A: bin edges by dst>>8 into tmp regions (block-privatized) -------
__global__ __launch_bounds__(256) void pass_a(const int* __restrict__ src,
                                              const int* __restrict__ dst,
                                              int* __restrict__ bnext,
                                              unsigned int* __restrict__ tmp) {
    __shared__ int cnt[NBUCK], loc[NBUCK], cur[NBUCK], gbase[NBUCK];
    __shared__ int s[256];
    __shared__ unsigned int stage[PA_CHUNK];
    __shared__ unsigned char sb[PA_CHUNK];
    int t = threadIdx.x;
    int base = blockIdx.x * PA_CHUNK;
    int len = N_EDGES - base; if (len > PA_CHUNK) len = PA_CHUNK;

    for (int i = t; i < NBUCK; i += 256) cnt[i] = 0;
    __syncthreads();
    for (int j = t; j < len; j += 256)
        atomicAdd(&cnt[dst[base + j] >> BUCK_SHIFT], 1);
    __syncthreads();
    int v = (t < NBUCK) ? cnt[t] : 0;
    s[t] = v;
    __syncthreads();
    for (int off = 1; off < 256; off <<= 1) {
        int u = (t >= off) ? s[t - off] : 0;
        __syncthreads();
        s[t] += u;
        __syncthreads();
    }
    if (t < NBUCK) {
        loc[t] = s[t] - v;
        cur[t] = s[t] - v;
        gbase[t] = v ? atomicAdd(&bnext[t], v) : 0;
    }
    __syncthreads();
    for (int j = t; j < len; j += 256) {
        int d = dst[base + j], s0 = src[base + j];
        int b = d >> BUCK_SHIFT;
        int r = atomicAdd(&cur[b], 1);
        stage[r] = ((unsigned)d << 16) | (unsigned)s0;
        sb[r] = (unsigned char)b;
    }
    __syncthreads();
    for (int j = t; j < len; j += 256) {
        int b = sb[j];
        tmp[gbase[b] + (j - loc[b])] = stage[j];
    }
}

// ---- pass B: per-bucket in-LDS counting sort -> csr_src, rowptr, dinv, rsq -
__global__ __launch_bounds__(256) void pass_b(const unsigned int* __restrict__ tmp,
                                              const int* __restrict__ bucketoff,
                                              int* __restrict__ rowptr,
                                              float* __restrict__ dinv,
                                              float* __restrict__ rsq,
                                              unsigned short* __restrict__ csr_src) {
    __shared__ int hist[256], ptr[256], cur[256];
    __shared__ unsigned int in[PB_CAP];
    __shared__ unsigned short outs[PB_CAP];
    int b = blockIdx.x, t = threadIdx.x;
    int base = bucketoff[b], end = bucketoff[b + 1];
    int k = end - base;
    int node0 = b << BUCK_SHIFT;
    int nloc = N_NODES - node0; if (nloc > 256) nloc = 256;

    hist[t] = 0;
    __syncthreads();
    bool fits = (k <= PB_CAP);
    for (int j = t; j < k; j += 256) {
        unsigned int w = tmp[base + j];
        if (fits) in[j] = w;
        atomicAdd(&hist[(w >> 16) & 255], 1);
    }
    __syncthreads();
    int v = hist[t];
    ptr[t] = v;
    __syncthreads();
    for (int off = 1; off < 256; off <<= 1) {
        int u = (t >= off) ? ptr[t - off] : 0;
        __syncthreads();
        ptr[t] += u;
        __syncthreads();
    }
    int excl = ptr[t] - v;
    cur[t] = excl;
    if (t < nloc) {
        rowptr[node0 + t] = base + excl;
        dinv[node0 + t] = v > 0 ? rsqrtf((float)v) : 0.0f;
        rsq[node0 + t]  = sqrtf((float)v);
    }
    __syncthreads();
    if (fits) {
        for (int j = t; j < k; j += 256) {
            unsigned int w = in[j];
            int r = atomicAdd(&cur[(w >> 16) & 255], 1);
            outs[r] = (unsigned short)(w & 0xFFFF);
        }
        __syncthreads();
        for (int j = t; j < k; j += 256) csr_src[base + j] = outs[j];
    } else {
        for (int j = t; j < k; j += 256) {
            unsigned int w = tmp[base + j];
            int r = atomicAdd(&cur[(w >> 16) & 255], 1);
            csr_src[base + r] = (unsigned short)(w & 0xFFFF);
        }
    }
}

// ---- device-scope grid barrier (all PULL_BLOCKS co-resident) ---------------
__device__ __forceinline__ void gbar(int* cnt, int nb) {
    __syncthreads();
    if (threadIdx.x == 0) {
        __threadfence();   // release: make this block's writes visible device-wide
        __hip_atomic_fetch_add(cnt, 1, __ATOMIC_ACQ_REL, __HIP_MEMORY_SCOPE_AGENT);
        while (__hip_atomic_load(cnt, __ATOMIC_ACQUIRE, __HIP_MEMORY_SCOPE_AGENT) < nb) {
            __builtin_amdgcn_s_sleep(1);
        }
        __threadfence();   // acquire: invalidate stale cached copies
    }
    __syncthreads();
}

// ---- per-phase pull body: one wave per dst node; 8 groups x 8 dims ---------
template <int FINAL>
__device__ __forceinline__ void pull_phase(
        int n0, int n1,
        const int* __restrict__ rowptr, const unsigned short* __restrict__ csr_src,
        const float* __restrict__ dinv, const __half* __restrict__ y,
        __half* __restrict__ y_out,
        const float* __restrict__ rsq, const __half* __restrict__ y1,
        const __half* __restrict__ y2, const float* __restrict__ emb,
        float* __restrict__ out) {
    int wave = threadIdx.x >> 6;
    int lane = threadIdx.x & 63;
    int g  = lane >> 3;     // group 0..7 (edge slot within chunk)
    int gl = lane & 7;      // lane in group (dim block)

    for (int node = n0 + wave; node < n1; node += 4) {
        int beg = rowptr[node];
        int end = rowptr[node + 1];

        float acc0 = 0.f, acc1 = 0.f, acc2 = 0.f, acc3 = 0.f;
        float acc4 = 0.f, acc5 = 0.f, acc6 = 0.f, acc7 = 0.f;

        for (int e0 = beg; e0 < end; e0 += 64) {
            int kk = end - e0; if (kk > 64) kk = 64;
            int idxv = (e0 + lane < end) ? (int)csr_src[e0 + lane] : 0;
            int nch = (kk + 7) >> 3;
            for (int i = 0; i < nch; ++i) {
                int pos = 8 * i + g;
                int s = __shfl(idxv, pos, 64);
                if (pos < kk) {
                    const uint4* p = (const uint4*)(y + (size_t)s * D + gl * 8);
                    uint4 v = *p;
                    const __half2* h = (const __half2*)&v;
                    float2 f0 = __half22float2(h[0]);
                    float2 f1 = __half22float2(h[1]);
                    float2 f2 = __half22float2(h[2]);
                    float2 f3 = __half22float2(h[3]);
                    acc0 += f0.x; acc1 += f0.y; acc2 += f1.x; acc3 += f1.y;
                    acc4 += f2.x; acc5 += f2.y; acc6 += f3.x; acc7 += f3.y;
                }
            }
        }

        #pragma unroll
        for (int off = 8; off < 64; off <<= 1) {
            acc0 += __shfl_xor(acc0, off, 64);
            acc1 += __shfl_xor(acc1, off, 64);
            acc2 += __shfl_xor(acc2, off, 64);
            acc3 += __shfl_xor(acc3, off, 64);
            acc4 += __shfl_xor(acc4, off, 64);
            acc5 += __shfl_xor(acc5, off, 64);
            acc6 += __shfl_xor(acc6, off, 64);
            acc7 += __shfl_xor(acc7, off, 64);
        }

        if (g == 0) {   // lanes 0..7 own dims gl*8..gl*8+7
            float dn = dinv[node];
            int base = node * D + gl * 8;
            if (FINAL == 0) {
                float s2 = dn * dn;
                __half2 h[4];
                h[0] = __floats2half2_rn(acc0 * s2, acc1 * s2);
                h[1] = __floats2half2_rn(acc2 * s2, acc3 * s2);
                h[2] = __floats2half2_rn(acc4 * s2, acc5 * s2);
                h[3] = __floats2half2_rn(acc6 * s2, acc7 * s2);
                *(uint4*)(y_out + base) = *(const uint4*)h;
            } else {
                float rs = rsq[node];
                uint4 v1 = *(const uint4*)(y1 + base);
                uint4 v2 = *(const uint4*)(y2 + base);
                const __half2* h1 = (const __half2*)&v1;
                const __half2* h2 = (const __half2*)&v2;
                float4 ea = *(const float4*)(emb + base);
                float4 eb = *(const float4*)(emb + base + 4);
                float2 a0 = __half22float2(h1[0]), b0 = __half22float2(h2[0]);
                float2 a1 = __half22float2(h1[1]), b1 = __half22float2(h2[1]);
                float2 a2 = __half22float2(h1[2]), b2 = __half22float2(h2[2]);
                float2 a3 = __half22float2(h1[3]), b3 = __half22float2(h2[3]);
                float4 o0, o1;
                o0.x = 0.25f * (ea.x + rs * (a0.x + b0.x) + dn * acc0);
                o0.y = 0.25f * (ea.y + rs * (a0.y + b0.y) + dn * acc1);
                o0.z = 0.25f * (ea.z + rs * (a1.x + b1.x) + dn * acc2);
                o0.w = 0.25f * (ea.w + rs * (a1.y + b1.y) + dn * acc3);
                o1.x = 0.25f * (eb.x + rs * (a2.x + b2.x) + dn * acc4);
                o1.y = 0.25f * (eb.y + rs * (a2.y + b2.y) + dn * acc5);
                o1.z = 0.25f * (eb.z + rs * (a3.x + b3.x) + dn * acc6);
                o1.w = 0.25f * (eb.w + rs * (a3.y + b3.y) + dn * acc7);
                *(float4*)(out + base)     = o0;
                *(float4*)(out + base + 4) = o1;
            }
        }
    }
}

// ---- fused persistent kernel: scale + 3 propagation layers -----------------
__global__ __launch_bounds__(256, 4) void pull_fused(
        const int* __restrict__ rowptr, const unsigned short* __restrict__ csr_src,
        const float* __restrict__ dinv, const float* __restrict__ rsq,
        const float* __restrict__ emb,
        __half* __restrict__ y0, __half* __restrict__ y1, __half* __restrict__ y2,
        float* __restrict__ out, int* __restrict__ bar) {
    int nb  = gridDim.x;
    int npb = (N_NODES + nb - 1) / nb;          // 49
    int n0 = blockIdx.x * npb;
    int n1 = n0 + npb; if (n1 > N_NODES) n1 = N_NODES;
    if (n0 > N_NODES) n0 = N_NODES;

    // phase 0: y0 = dinv * emb   (element-parallel, coalesced)
    {
        int e0 = n0 * D, e1 = n1 * D;
        for (int j = e0 + (int)threadIdx.x; j < e1; j += 256)
            y0[j] = __float2half(emb[j] * dinv[j >> 6]);
    }
    gbar(bar + 0, nb);
    // phase 1: y1 = A_s y0
    pull_phase<0>(n0, n1, rowptr, csr_src, dinv, y0, y1,
                  nullptr, nullptr, nullptr, nullptr, nullptr);
    gbar(bar + 1, nb);
    // phase 2: y2 = A_s y1
    pull_phase<0>(n0, n1, rowptr, csr_src, dinv, y1, y2,
                  nullptr, nullptr, nullptr, nullptr, nullptr);
    gbar(bar + 2, nb);
    // phase 3: out = 0.25*(emb + rsq*(y1+y2) + dinv*sum(y2))
    pull_phase<1>(n0, n1, rowptr, csr_src, dinv, y2, nullptr,
                  rsq, y1, y2, emb, out);
}

extern "C" void kernel_launch(void* const* d_in, const int* in_sizes, int n_in,
                              void* d_out, int out_size, void* d_ws, size_t ws_size,
                              hipStream_t stream) {
    const int*   ei  = (const int*)d_in[0];     // (2, E) int32, row-major
    const float* emb = (const float*)d_in[1];   // (N, D) fp32
    const int* src = ei;
    const int* dst = ei + N_EDGES;
    float* out = (float*)d_out;

    // workspace layout
    int* bhist      = (int*)d_ws;                          // NBUCK
    int* bucketoff  = bhist + NBUCK;                       // NBUCK+1
    int* bnext      = bucketoff + (NBUCK + 1);             // NBUCK
    int* bar        = bnext + NBUCK;                       // 3 (grid barrier counters)
    int* rowptr     = bar + 3 + 1;                         // N+1 (keep alignment)
    unsigned int*   tmp     = (unsigned int*)(rowptr + N_NODES + 1);   // E (4B)
    unsigned short* csr_src = (unsigned short*)(tmp + N_EDGES);        // E (2B)
    float* dinv = (float*)(csr_src + N_EDGES);             // N
    float* rsq  = dinv + N_NODES;                          // N
    __half* y0  = (__half*)(rsq + N_NODES);                // N*D
    __half* y1  = y0 + (size_t)N_NODES * D;                // N*D
    __half* y2  = y1 + (size_t)N_NODES * D;                // N*D

    hipMemsetAsync(bar, 0, 3 * sizeof(int), stream);
    zero_bhist<<<1, 256, 0, stream>>>(bhist);
    bucket_hist<<<512, 256, 0, stream>>>(dst, bhist);
    bucket_scan<<<1, 256, 0, stream>>>(bhist, bucketoff, bnext, rowptr);
    pass_a<<<PA_BLOCKS, 256, 0, stream>>>(src, dst, bnext, tmp);
    pass_b<<<NBUCK, 256, 0, stream>>>(tmp, bucketoff, rowptr, dinv, rsq, csr_src);

    pull_fused<<<PULL_BLOCKS, 256, 0, stream>>>(rowptr, csr_src, dinv, rsq, emb,
                                                y0, y1, y2, out, bar);
}

// Round 10
// 187.740 us; speedup vs baseline: 3.4404x; 3.4404x over previous
//
#include <hip/hip_runtime.h>
#include <hip/hip_fp16.h>

#define N_NODES 50000
#define N_EDGES 800000
#define D 64
#define NBUCK 196                 // ceil(N_NODES / 256)
#define BUCK_SHIFT 8
#define PA_CHUNK 2048
#define PA_BLOCKS ((N_EDGES + PA_CHUNK - 1) / PA_CHUNK)   // 391
#define PB_CAP 8192               // Poisson(4082) never reaches this; fallback kept anyway

// ---- tiny init -------------------------------------------------------------
__global__ void zero_bhist(int* __restrict__ bhist) {
    int t = threadIdx.x;
    if (t < NBUCK) bhist[t] = 0;
}

// ---- coarse 196-bucket histogram of dst (LDS-privatized) -------------------
__global__ __launch_bounds__(256) void bucket_hist(const int* __restrict__ dst,
                                                   int* __restrict__ bhist) {
    __shared__ int h[NBUCK];
    for (int i = threadIdx.x; i < NBUCK; i += 256) h[i] = 0;
    __syncthreads();
    int stride = gridDim.x * 256;
    for (int e = blockIdx.x * 256 + threadIdx.x; e < N_EDGES; e += stride)
        atomicAdd(&h[dst[e] >> BUCK_SHIFT], 1);
    __syncthreads();
    for (int i = threadIdx.x; i < NBUCK; i += 256)
        if (h[i]) atomicAdd(&bhist[i], h[i]);
}

// ---- 1-block scan of 196 bucket counts -> bucketoff / bnext ---------------
__global__ __launch_bounds__(256) void bucket_scan(const int* __restrict__ bhist,
                                                   int* __restrict__ bucketoff,
                                                   int* __restrict__ bnext,
                                                   int* __restrict__ rowptr) {
    __shared__ int lds[256];
    int t = threadIdx.x;
    int v = (t < NBUCK) ? bhist[t] : 0;
    lds[t] = v;
    __syncthreads();
    for (int off = 1; off < 256; off <<= 1) {
        int u = (t >= off) ? lds[t - off] : 0;
        __syncthreads();
        lds[t] += u;
        __syncthreads();
    }
    if (t < NBUCK) { bucketoff[t] = lds[t] - v; bnext[t] = lds[t] - v; }
    if (t == 0)    { bucketoff[NBUCK] = N_EDGES; rowptr[N_NODES] = N_EDGES; }
}

// ---- pass A: bin edges by dst>>8 into tmp regions (block-privatized) -------
__global__ __launch_bounds__(256) void pass_a(const int* __restrict__ src,
                                              const int* __restrict__ dst,
                                              int* __restrict__ bnext,
                                              unsigned int* __restrict__ tmp) {
    __shared__ int cnt[NBUCK], loc[NBUCK], cur[NBUCK], gbase[NBUCK];
    __shared__ int s[256];
    __shared__ unsigned int stage[PA_CHUNK];
    __shared__ unsigned char sb[PA_CHUNK];
    int t = threadIdx.x;
    int base = blockIdx.x * PA_CHUNK;
    int len = N_EDGES - base; if (len > PA_CHUNK) len = PA_CHUNK;

    for (int i = t; i < NBUCK; i += 256) cnt[i] = 0;
    __syncthreads();
    for (int j = t; j < len; j += 256)
        atomicAdd(&cnt[dst[base + j] >> BUCK_SHIFT], 1);
    __syncthreads();
    int v = (t < NBUCK) ? cnt[t] : 0;
    s[t] = v;
    __syncthreads();
    for (int off = 1; off < 256; off <<= 1) {
        int u = (t >= off) ? s[t - off] : 0;
        __syncthreads();
        s[t] += u;
        __syncthreads();
    }
    if (t < NBUCK) {
        loc[t] = s[t] - v;
        cur[t] = s[t] - v;
        gbase[t] = v ? atomicAdd(&bnext[t], v) : 0;
    }
    __syncthreads();
    for (int j = t; j < len; j += 256) {
        int d = dst[base + j], s0 = src[base + j];
        int b = d >> BUCK_SHIFT;
        int r = atomicAdd(&cur[b], 1);
        stage[r] = ((unsigned)d << 16) | (unsigned)s0;
        sb[r] = (unsigned char)b;
    }
    __syncthreads();
    for (int j = t; j < len; j += 256) {
        int b = sb[j];
        tmp[gbase[b] + (j - loc[b])] = stage[j];
    }
}

// ---- pass B: per-bucket in-LDS counting sort -> csr_src, rowptr, dinv, rsq -
__global__ __launch_bounds__(256) void pass_b(const unsigned int* __restrict__ tmp,
                                              const int* __restrict__ bucketoff,
                                              int* __restrict__ rowptr,
                                              float* __restrict__ dinv,
                                              float* __restrict__ rsq,
                                              unsigned short* __restrict__ csr_src) {
    __shared__ int hist[256], ptr[256], cur[256];
    __shared__ unsigned int in[PB_CAP];
    __shared__ unsigned short outs[PB_CAP];
    int b = blockIdx.x, t = threadIdx.x;
    int base = bucketoff[b], end = bucketoff[b + 1];
    int k = end - base;
    int node0 = b << BUCK_SHIFT;
    int nloc = N_NODES - node0; if (nloc > 256) nloc = 256;

    hist[t] = 0;
    __syncthreads();
    bool fits = (k <= PB_CAP);
    for (int j = t; j < k; j += 256) {
        unsigned int w = tmp[base + j];
        if (fits) in[j] = w;
        atomicAdd(&hist[(w >> 16) & 255], 1);
    }
    __syncthreads();
    int v = hist[t];
    ptr[t] = v;
    __syncthreads();
    for (int off = 1; off < 256; off <<= 1) {
        int u = (t >= off) ? ptr[t - off] : 0;
        __syncthreads();
        ptr[t] += u;
        __syncthreads();
    }
    int excl = ptr[t] - v;
    cur[t] = excl;
    if (t < nloc) {
        rowptr[node0 + t] = base + excl;
        dinv[node0 + t] = v > 0 ? rsqrtf((float)v) : 0.0f;
        rsq[node0 + t]  = sqrtf((float)v);
    }
    __syncthreads();
    if (fits) {
        for (int j = t; j < k; j += 256) {
            unsigned int w = in[j];
            int r = atomicAdd(&cur[(w >> 16) & 255], 1);
            outs[r] = (unsigned short)(w & 0xFFFF);
        }
        __syncthreads();
        for (int j = t; j < k; j += 256) csr_src[base + j] = outs[j];
    } else {
        for (int j = t; j < k; j += 256) {
            unsigned int w = tmp[base + j];
            int r = atomicAdd(&cur[(w >> 16) & 255], 1);
            csr_src[base + r] = (unsigned short)(w & 0xFFFF);
        }
    }
}

// ---- y0 halves: y0h[half][n*32+dl] = dinv[n] * emb[n*64 + half*32 + dl] ----
// one thread = 8 contiguous fp16 (one uint4 store)
__global__ void scale_kernel(const float* __restrict__ emb, const float* __restrict__ dinv,
                             __half* __restrict__ yh0, __half* __restrict__ yh1, int total8) {
    int i = blockIdx.x * blockDim.x + threadIdx.x;
    if (i < total8) {
        int j0 = i * 8;
        int n = j0 >> 6;
        int d = j0 & 63;
        float s = dinv[n];
        float4 a = *(const float4*)(emb + j0);
        float4 b = *(const float4*)(emb + j0 + 4);
        __half2 h[4];
        h[0] = __floats2half2_rn(a.x * s, a.y * s);
        h[1] = __floats2half2_rn(a.z * s, a.w * s);
        h[2] = __floats2half2_rn(b.x * s, b.y * s);
        h[3] = __floats2half2_rn(b.z * s, b.w * s);
        __half* dstp = (d < 32 ? yh0 : yh1) + n * 32 + (d & 31);
        *(uint4*)dstp = *(const uint4*)h;
    }
}

// ---- half-row pull: one wave per dst node; 16 groups x 4 lanes x 8 dims ----
// y arrays hold 32 dims/node (64B row = ONE cache line). One gather instr
// fetches 16 half-rows. Working set 3.2MB -> resident in each XCD's 4MB L2.
// FINAL=0: y_out = dinv^2 * acc
// FINAL=1: x3 = dinv*acc; out[.,dimoff+0..31] = 0.25*(emb + rsq*(y1h+y2h) + x3)
template <int FINAL>
__global__ __launch_bounds__(256) void pull_half(
        const int* __restrict__ rowptr, const unsigned short* __restrict__ csr_src,
        const float* __restrict__ dinv, const __half* __restrict__ y,
        __half* __restrict__ y_out,
        const float* __restrict__ rsq, const __half* __restrict__ y1h,
        const __half* __restrict__ y2h, const float* __restrict__ emb,
        float* __restrict__ out, int dimoff) {
    int node = blockIdx.x * 4 + (threadIdx.x >> 6);
    int lane = threadIdx.x & 63;
    if (node >= N_NODES) return;
    int beg = rowptr[node];
    int end = rowptr[node + 1];
    int g  = lane >> 2;     // group 0..15 (edge slot within chunk)
    int gl = lane & 3;      // lane in group: dims gl*8..gl*8+7

    float a0 = 0.f, a1 = 0.f, a2 = 0.f, a3 = 0.f;
    float a4 = 0.f, a5 = 0.f, a6 = 0.f, a7 = 0.f;

    for (int e0 = beg; e0 < end; e0 += 64) {
        int kk = end - e0; if (kk > 64) kk = 64;
        // one coalesced 128B load fetches up to 64 edge indices for this wave
        int idxv = (e0 + lane < end) ? (int)csr_src[e0 + lane] : 0;
        int nch = (kk + 15) >> 4;
        for (int i = 0; i < nch; ++i) {
            int pos = 16 * i + g;
            int s = __shfl(idxv, pos, 64);   // group's src node for this chunk
            if (pos < kk) {
                uint4 v = *(const uint4*)(y + s * 32 + gl * 8);   // 8 fp16 dims
                const __half2* h = (const __half2*)&v;
                float2 f0 = __half22float2(h[0]);
                float2 f1 = __half22float2(h[1]);
                float2 f2 = __half22float2(h[2]);
                float2 f3 = __half22float2(h[3]);
                a0 += f0.x; a1 += f0.y; a2 += f1.x; a3 += f1.y;
                a4 += f2.x; a5 += f2.y; a6 += f3.x; a7 += f3.y;
            }
        }
    }

    // cross-group reduce: 16 groups hold partials of the same 8 dims
    #pragma unroll
    for (int off = 4; off < 64; off <<= 1) {
        a0 += __shfl_xor(a0, off, 64);
        a1 += __shfl_xor(a1, off, 64);
        a2 += __shfl_xor(a2, off, 64);
        a3 += __shfl_xor(a3, off, 64);
        a4 += __shfl_xor(a4, off, 64);
        a5 += __shfl_xor(a5, off, 64);
        a6 += __shfl_xor(a6, off, 64);
        a7 += __shfl_xor(a7, off, 64);
    }

    if (g == 0) {   // lanes 0..3 own dims gl*8..gl*8+7
        float dn = dinv[node];
        if (FINAL == 0) {
            float s2 = dn * dn;
            __half2 h[4];
            h[0] = __floats2half2_rn(a0 * s2, a1 * s2);
            h[1] = __floats2half2_rn(a2 * s2, a3 * s2);
            h[2] = __floats2half2_rn(a4 * s2, a5 * s2);
            h[3] = __floats2half2_rn(a6 * s2, a7 * s2);
            *(uint4*)(y_out + node * 32 + gl * 8) = *(const uint4*)h;
        } else {
            float rs = rsq[node];
            int hb = node * 32 + gl * 8;
            uint4 v1 = *(const uint4*)(y1h + hb);
            uint4 v2 = *(const uint4*)(y2h + hb);
            const __half2* h1 = (const __half2*)&v1;
            const __half2* h2 = (const __half2*)&v2;
            int ob = node * D + dimoff + gl * 8;
            float4 ea = *(const float4*)(emb + ob);
            float4 eb = *(const float4*)(emb + ob + 4);
            float2 p0 = __half22float2(h1[0]), q0 = __half22float2(h2[0]);
            float2 p1 = __half22float2(h1[1]), q1 = __half22float2(h2[1]);
            float2 p2 = __half22float2(h1[2]), q2 = __half22float2(h2[2]);
            float2 p3 = __half22float2(h1[3]), q3 = __half22float2(h2[3]);
            float4 o0, o1;
            o0.x = 0.25f * (ea.x + rs * (p0.x + q0.x) + dn * a0);
            o0.y = 0.25f * (ea.y + rs * (p0.y + q0.y) + dn * a1);
            o0.z = 0.25f * (ea.z + rs * (p1.x + q1.x) + dn * a2);
            o0.w = 0.25f * (ea.w + rs * (p1.y + q1.y) + dn * a3);
            o1.x = 0.25f * (eb.x + rs * (p2.x + q2.x) + dn * a4);
            o1.y = 0.25f * (eb.y + rs * (p2.y + q2.y) + dn * a5);
            o1.z = 0.25f * (eb.z + rs * (p3.x + q3.x) + dn * a6);
            o1.w = 0.25f * (eb.w + rs * (p3.y + q3.y) + dn * a7);
            *(float4*)(out + ob)     = o0;
            *(float4*)(out + ob + 4) = o1;
        }
    }
}

extern "C" void kernel_launch(void* const* d_in, const int* in_sizes, int n_in,
                              void* d_out, int out_size, void* d_ws, size_t ws_size,
                              hipStream_t stream) {
    const int*   ei  = (const int*)d_in[0];     // (2, E) int32, row-major
    const float* emb = (const float*)d_in[1];   // (N, D) fp32
    const int* src = ei;
    const int* dst = ei + N_EDGES;
    float* out = (float*)d_out;

    // workspace layout (int units, 16B-aligned sections)
    int* base = (int*)d_ws;
    int* bhist      = base + 0;          // 196
    int* bucketoff  = base + 196;        // 197
    int* bnext      = base + 393;        // 196 -> 589, pad to 592
    int* rowptr     = base + 592;        // 50001 -> 50593, pad to 50596
    unsigned int*   tmp     = (unsigned int*)(base + 50596);      // 800000
    unsigned short* csr_src = (unsigned short*)(base + 850596);   // 800000 ushort
    float* dinv = (float*)(base + 1250596);   // 50000
    float* rsq  = (float*)(base + 1300596);   // 50000 -> ends 1350596 (16B aligned)
    __half* yh[3][2];
    for (int k = 0; k < 3; ++k)
        for (int h = 0; h < 2; ++h)
            yh[k][h] = (__half*)(base + 1350596 + (size_t)(k * 2 + h) * 800000);

    zero_bhist<<<1, 256, 0, stream>>>(bhist);
    bucket_hist<<<512, 256, 0, stream>>>(dst, bhist);
    bucket_scan<<<1, 256, 0, stream>>>(bhist, bucketoff, bnext, rowptr);
    pass_a<<<PA_BLOCKS, 256, 0, stream>>>(src, dst, bnext, tmp);
    pass_b<<<NBUCK, 256, 0, stream>>>(tmp, bucketoff, rowptr, dinv, rsq, csr_src);
    scale_kernel<<<((N_NODES * D / 8) + 255) / 256, 256, 0, stream>>>(
        emb, dinv, yh[0][0], yh[0][1], N_NODES * D / 8);

    const int pull_blocks = (N_NODES + 3) / 4;   // 12500
    for (int h = 0; h < 2; ++h) {
        // y1h = A_s y0h
        pull_half<0><<<pull_blocks, 256, 0, stream>>>(rowptr, csr_src, dinv,
            yh[0][h], yh[1][h], nullptr, nullptr, nullptr, nullptr, nullptr, 0);
        // y2h = A_s y1h
        pull_half<0><<<pull_blocks, 256, 0, stream>>>(rowptr, csr_src, dinv,
            yh[1][h], yh[2][h], nullptr, nullptr, nullptr, nullptr, nullptr, 0);
        // out half = 0.25*(emb + rsq*(y1h+y2h) + dinv*sum(y2h))
        pull_half<1><<<pull_blocks, 256, 0, stream>>>(rowptr, csr_src, dinv,
            yh[2][h], nullptr, rsq, yh[1][h], yh[2][h], emb, out, h * 32);
    }
}

// Round 11
// 126.943 us; speedup vs baseline: 5.0882x; 1.4789x over previous
//
#include <hip/hip_runtime.h>
#include <hip/hip_fp16.h>

#define N_NODES 50000
#define N_EDGES 800000
#define D 64
#define NBUCK 196                 // ceil(N_NODES / 256)
#define BUCK_SHIFT 8
#define PA_CHUNK 2048
#define PA_BLOCKS ((N_EDGES + PA_CHUNK - 1) / PA_CHUNK)   // 391
#define PB_CAP 8192               // Poisson(4082) never reaches this; fallback kept anyway
#define PULL_GRID 2048            // 8 blocks/CU, grid-stride over nodes

// ---- tiny init -------------------------------------------------------------
__global__ void zero_bhist(int* __restrict__ bhist) {
    int t = threadIdx.x;
    if (t < NBUCK) bhist[t] = 0;
}

// ---- coarse 196-bucket histogram of dst (LDS-privatized) -------------------
__global__ __launch_bounds__(256) void bucket_hist(const int* __restrict__ dst,
                                                   int* __restrict__ bhist) {
    __shared__ int h[NBUCK];
    for (int i = threadIdx.x; i < NBUCK; i += 256) h[i] = 0;
    __syncthreads();
    int stride = gridDim.x * 256;
    for (int e = blockIdx.x * 256 + threadIdx.x; e < N_EDGES; e += stride)
        atomicAdd(&h[dst[e] >> BUCK_SHIFT], 1);
    __syncthreads();
    for (int i = threadIdx.x; i < NBUCK; i += 256)
        if (h[i]) atomicAdd(&bhist[i], h[i]);
}

// ---- 1-block scan of 196 bucket counts -> bucketoff / bnext ---------------
__global__ __launch_bounds__(256) void bucket_scan(const int* __restrict__ bhist,
                                                   int* __restrict__ bucketoff,
                                                   int* __restrict__ bnext,
                                                   int* __restrict__ rowptr) {
    __shared__ int lds[256];
    int t = threadIdx.x;
    int v = (t < NBUCK) ? bhist[t] : 0;
    lds[t] = v;
    __syncthreads();
    for (int off = 1; off < 256; off <<= 1) {
        int u = (t >= off) ? lds[t - off] : 0;
        __syncthreads();
        lds[t] += u;
        __syncthreads();
    }
    if (t < NBUCK) { bucketoff[t] = lds[t] - v; bnext[t] = lds[t] - v; }
    if (t == 0)    { bucketoff[NBUCK] = N_EDGES; rowptr[N_NODES] = N_EDGES; }
}

// ---- pass A: bin edges by dst>>8 into tmp regions (block-privatized) -------
__global__ __launch_bounds__(256) void pass_a(const int* __restrict__ src,
                                              const int* __restrict__ dst,
                                              int* __restrict__ bnext,
                                              unsigned int* __restrict__ tmp) {
    __shared__ int cnt[NBUCK], loc[NBUCK], cur[NBUCK], gbase[NBUCK];
    __shared__ int s[256];
    __shared__ unsigned int stage[PA_CHUNK];
    __shared__ unsigned char sb[PA_CHUNK];
    int t = threadIdx.x;
    int base = blockIdx.x * PA_CHUNK;
    int len = N_EDGES - base; if (len > PA_CHUNK) len = PA_CHUNK;

    for (int i = t; i < NBUCK; i += 256) cnt[i] = 0;
    __syncthreads();
    for (int j = t; j < len; j += 256)
        atomicAdd(&cnt[dst[base + j] >> BUCK_SHIFT], 1);
    __syncthreads();
    int v = (t < NBUCK) ? cnt[t] : 0;
    s[t] = v;
    __syncthreads();
    for (int off = 1; off < 256; off <<= 1) {
        int u = (t >= off) ? s[t - off] : 0;
        __syncthreads();
        s[t] += u;
        __syncthreads();
    }
    if (t < NBUCK) {
        loc[t] = s[t] - v;
        cur[t] = s[t] - v;
        gbase[t] = v ? atomicAdd(&bnext[t], v) : 0;
    }
    __syncthreads();
    for (int j = t; j < len; j += 256) {
        int d = dst[base + j], s0 = src[base + j];
        int b = d >> BUCK_SHIFT;
        int r = atomicAdd(&cur[b], 1);
        stage[r] = ((unsigned)d << 16) | (unsigned)s0;
        sb[r] = (unsigned char)b;
    }
    __syncthreads();
    for (int j = t; j < len; j += 256) {
        int b = sb[j];
        tmp[gbase[b] + (j - loc[b])] = stage[j];
    }
}

// ---- pass B: per-bucket counting sort -> csr_src, rowptr, dinv, rsq; also
// writes y0 rows for its 256-node range (fused former scale_kernel) ---------
__global__ __launch_bounds__(256) void pass_b(const unsigned int* __restrict__ tmp,
                                              const int* __restrict__ bucketoff,
                                              int* __restrict__ rowptr,
                                              float* __restrict__ dinv,
                                              float* __restrict__ rsq,
                                              unsigned short* __restrict__ csr_src,
                                              const float* __restrict__ emb,
                                              __half* __restrict__ y0) {
    __shared__ int hist[256], ptr[256], cur[256];
    __shared__ float sdinv[256];
    __shared__ unsigned int in[PB_CAP];
    __shared__ unsigned short outs[PB_CAP];
    int b = blockIdx.x, t = threadIdx.x;
    int base = bucketoff[b], end = bucketoff[b + 1];
    int k = end - base;
    int node0 = b << BUCK_SHIFT;
    int nloc = N_NODES - node0; if (nloc > 256) nloc = 256;

    hist[t] = 0;
    __syncthreads();
    bool fits = (k <= PB_CAP);
    for (int j = t; j < k; j += 256) {
        unsigned int w = tmp[base + j];
        if (fits) in[j] = w;
        atomicAdd(&hist[(w >> 16) & 255], 1);
    }
    __syncthreads();
    int v = hist[t];
    ptr[t] = v;
    __syncthreads();
    for (int off = 1; off < 256; off <<= 1) {
        int u = (t >= off) ? ptr[t - off] : 0;
        __syncthreads();
        ptr[t] += u;
        __syncthreads();
    }
    int excl = ptr[t] - v;
    cur[t] = excl;
    if (t < nloc) {
        float dn = v > 0 ? rsqrtf((float)v) : 0.0f;
        rowptr[node0 + t] = base + excl;
        dinv[node0 + t] = dn;
        rsq[node0 + t]  = sqrtf((float)v);
        sdinv[t] = dn;
    }
    __syncthreads();
    if (fits) {
        for (int j = t; j < k; j += 256) {
            unsigned int w = in[j];
            int r = atomicAdd(&cur[(w >> 16) & 255], 1);
            outs[r] = (unsigned short)(w & 0xFFFF);
        }
        __syncthreads();
        for (int j = t; j < k; j += 256) csr_src[base + j] = outs[j];
    } else {
        for (int j = t; j < k; j += 256) {
            unsigned int w = tmp[base + j];
            int r = atomicAdd(&cur[(w >> 16) & 255], 1);
            csr_src[base + r] = (unsigned short)(w & 0xFFFF);
        }
    }

    // fused scale: y0[n,:] = dinv[n] * emb[n,:] for this bucket's nodes
    int nv = nloc * 8;                    // uint4 stores (8 fp16 each)
    for (int q = t; q < nv; q += 256) {
        int n   = q >> 3;
        int off = (q & 7) * 8;
        float s = sdinv[n];
        const float* ep = emb + (size_t)(node0 + n) * D + off;
        float4 a = *(const float4*)ep;
        float4 bb = *(const float4*)(ep + 4);
        __half2 h[4];
        h[0] = __floats2half2_rn(a.x * s, a.y * s);
        h[1] = __floats2half2_rn(a.z * s, a.w * s);
        h[2] = __floats2half2_rn(bb.x * s, bb.y * s);
        h[3] = __floats2half2_rn(bb.z * s, bb.w * s);
        *(uint4*)(y0 + (size_t)(node0 + n) * D + off) = *(const uint4*)h;
    }
}

// ---- pull: grid-stride, one wave per dst node; 8 groups x 8 dims -----------
// One VMEM instr fetches 8 full 128B rows. FINAL=0: y_out = dinv^2 * acc.
// FINAL=1: x3 = dinv*acc; out = 0.25*(emb + rsq*(y1+y2) + x3)
template <int FINAL>
__global__ __launch_bounds__(256) void pull_kernel(
        const int* __restrict__ rowptr, const unsigned short* __restrict__ csr_src,
        const float* __restrict__ dinv, const __half* __restrict__ y,
        __half* __restrict__ y_out,
        const float* __restrict__ rsq, const __half* __restrict__ y1,
        const __half* __restrict__ y2, const float* __restrict__ emb,
        float* __restrict__ out) {
    int lane = threadIdx.x & 63;
    int g  = lane >> 3;     // group 0..7 (edge slot within chunk)
    int gl = lane & 7;      // lane in group (dim block)
    int node0 = blockIdx.x * 4 + (threadIdx.x >> 6);

    for (int node = node0; node < N_NODES; node += PULL_GRID * 4) {
        int beg = rowptr[node];
        int end = rowptr[node + 1];

        float acc0 = 0.f, acc1 = 0.f, acc2 = 0.f, acc3 = 0.f;
        float acc4 = 0.f, acc5 = 0.f, acc6 = 0.f, acc7 = 0.f;

        for (int e0 = beg; e0 < end; e0 += 64) {
            int kk = end - e0; if (kk > 64) kk = 64;
            int idxv = (e0 + lane < end) ? (int)csr_src[e0 + lane] : 0;
            int nch = (kk + 7) >> 3;
            for (int i = 0; i < nch; ++i) {
                int pos = 8 * i + g;
                int s = __shfl(idxv, pos, 64);
                if (pos < kk) {
                    const uint4* p = (const uint4*)(y + (size_t)s * D + gl * 8);
                    uint4 v = *p;
                    const __half2* h = (const __half2*)&v;
                    float2 f0 = __half22float2(h[0]);
                    float2 f1 = __half22float2(h[1]);
                    float2 f2 = __half22float2(h[2]);
                    float2 f3 = __half22float2(h[3]);
                    acc0 += f0.x; acc1 += f0.y; acc2 += f1.x; acc3 += f1.y;
                    acc4 += f2.x; acc5 += f2.y; acc6 += f3.x; acc7 += f3.y;
                }
            }
        }

        #pragma unroll
        for (int off = 8; off < 64; off <<= 1) {
            acc0 += __shfl_xor(acc0, off, 64);
            acc1 += __shfl_xor(acc1, off, 64);
            acc2 += __shfl_xor(acc2, off, 64);
            acc3 += __shfl_xor(acc3, off, 64);
            acc4 += __shfl_xor(acc4, off, 64);
            acc5 += __shfl_xor(acc5, off, 64);
            acc6 += __shfl_xor(acc6, off, 64);
            acc7 += __shfl_xor(acc7, off, 64);
        }

        if (g == 0) {   // lanes 0..7 own dims gl*8..gl*8+7
            float dn = dinv[node];
            int base = node * D + gl * 8;
            if (FINAL == 0) {
                float s2 = dn * dn;
                __half2 h[4];
                h[0] = __floats2half2_rn(acc0 * s2, acc1 * s2);
                h[1] = __floats2half2_rn(acc2 * s2, acc3 * s2);
                h[2] = __floats2half2_rn(acc4 * s2, acc5 * s2);
                h[3] = __floats2half2_rn(acc6 * s2, acc7 * s2);
                *(uint4*)(y_out + base) = *(const uint4*)h;
            } else {
                float rs = rsq[node];
                uint4 v1 = *(const uint4*)(y1 + base);
                uint4 v2 = *(const uint4*)(y2 + base);
                const __half2* h1 = (const __half2*)&v1;
                const __half2* h2 = (const __half2*)&v2;
                float4 ea = *(const float4*)(emb + base);
                float4 eb = *(const float4*)(emb + base + 4);
                float2 a0 = __half22float2(h1[0]), b0 = __half22float2(h2[0]);
                float2 a1 = __half22float2(h1[1]), b1 = __half22float2(h2[1]);
                float2 a2 = __half22float2(h1[2]), b2 = __half22float2(h2[2]);
                float2 a3 = __half22float2(h1[3]), b3 = __half22float2(h2[3]);
                float4 o0, o1;
                o0.x = 0.25f * (ea.x + rs * (a0.x + b0.x) + dn * acc0);
                o0.y = 0.25f * (ea.y + rs * (a0.y + b0.y) + dn * acc1);
                o0.z = 0.25f * (ea.z + rs * (a1.x + b1.x) + dn * acc2);
                o0.w = 0.25f * (ea.w + rs * (a1.y + b1.y) + dn * acc3);
                o1.x = 0.25f * (eb.x + rs * (a2.x + b2.x) + dn * acc4);
                o1.y = 0.25f * (eb.y + rs * (a2.y + b2.y) + dn * acc5);
                o1.z = 0.25f * (eb.z + rs * (a3.x + b3.x) + dn * acc6);
                o1.w = 0.25f * (eb.w + rs * (a3.y + b3.y) + dn * acc7);
                *(float4*)(out + base)     = o0;
                *(float4*)(out + base + 4) = o1;
            }
        }
    }
}

extern "C" void kernel_launch(void* const* d_in, const int* in_sizes, int n_in,
                              void* d_out, int out_size, void* d_ws, size_t ws_size,
                              hipStream_t stream) {
    const int*   ei  = (const int*)d_in[0];     // (2, E) int32, row-major
    const float* emb = (const float*)d_in[1];   // (N, D) fp32
    const int* src = ei;
    const int* dst = ei + N_EDGES;
    float* out = (float*)d_out;

    // workspace layout (int units; section starts kept 16B-aligned)
    int* base = (int*)d_ws;
    int* bhist      = base + 0;          // 196
    int* bucketoff  = base + 196;        // 197
    int* bnext      = base + 396;        // 196 -> 592
    int* rowptr     = base + 592;        // 50001 -> pad to 50596
    unsigned int*   tmp     = (unsigned int*)(base + 50596);      // 800000
    unsigned short* csr_src = (unsigned short*)(base + 850596);   // 800000 ushort -> 400000 ints
    float* dinv = (float*)(base + 1250596);   // 50000
    float* rsq  = (float*)(base + 1300596);   // 50000 -> ends 1350596
    __half* y0  = (__half*)(base + 1350596);              // N*D fp16 = 1.6M ints
    __half* y1  = y0 + (size_t)N_NODES * D;
    __half* y2  = y1 + (size_t)N_NODES * D;

    zero_bhist<<<1, 256, 0, stream>>>(bhist);
    bucket_hist<<<512, 256, 0, stream>>>(dst, bhist);
    bucket_scan<<<1, 256, 0, stream>>>(bhist, bucketoff, bnext, rowptr);
    pass_a<<<PA_BLOCKS, 256, 0, stream>>>(src, dst, bnext, tmp);
    pass_b<<<NBUCK, 256, 0, stream>>>(tmp, bucketoff, rowptr, dinv, rsq, csr_src,
                                      emb, y0);

    // y1 = A_s y0
    pull_kernel<0><<<PULL_GRID, 256, 0, stream>>>(rowptr, csr_src, dinv, y0, y1,
                                                  nullptr, nullptr, nullptr, nullptr, nullptr);
    // y2 = A_s y1
    pull_kernel<0><<<PULL_GRID, 256, 0, stream>>>(rowptr, csr_src, dinv, y1, y2,
                                                  nullptr, nullptr, nullptr, nullptr, nullptr);
    // out = 0.25*(emb + rsq*(y1+y2) + dinv*sum(y2))
    pull_kernel<1><<<PULL_GRID, 256, 0, stream>>>(rowptr, csr_src, dinv, y2, nullptr,
                                                  rsq, y1, y2, emb, out);
}